// Round 4
// baseline (746.354 us; speedup 1.0000x reference)
//
#include <hip/hip_runtime.h>
#include <hip/hip_bf16.h>

// GCN: 3x GCNConv(relu) -> mean over layers -> global mean pool -> linear -> softmax
// N=100000, E=3200000, F_IN=128, F_HID=64, F_OUT=10, G=1000.
//
// out[dst] = dinv[dst] * ( sum_{e: row[e]=dst} z[col[e]] + z[dst] ) + b,
// z = (x @ W) * dinv[:,None], dinv = rsqrt(deg_col + 1).
//
// R3 changes: (1) bin_edges 1024-thread blocks (was 7% occupancy) + packed
// 4B/1B sort records; (2) build_csr 1024 threads + inline bucket prefix
// (scan kernel removed); (3) Z split into two 6.4MB feature-halves, aggregate
// runs per-half device-wide so the gather working set fits per-XCD L2 better;
// (4) pool_head 256 threads.

#define ALIGN_UP(x, a) (((x) + (a) - 1) / (a) * (a))
#define NBMAX 512        // max buckets (node id >> 8), supports n <= 131072
#define BCAP  10240      // entries per bucket region (mean 8192, +22 sigma)

__device__ __forceinline__ float bf16_to_f32(ushort u) {
    return __uint_as_float(((unsigned)u) << 16);
}
__device__ __forceinline__ unsigned pack_bf16(float a, float b) {
    union { __hip_bfloat16 h; ushort u; } ua, ub;
    ua.h = __float2bfloat16(a); ub.h = __float2bfloat16(b);
    return (unsigned)ua.u | ((unsigned)ub.u << 16);
}

// ---------------- Pass A: bin edges; RB=(col<<8)|(row&255) uint, CB=col&255 uchar ----------------
__global__ __launch_bounds__(1024) void bin_edges(const int* __restrict__ row,
                                                  const int* __restrict__ col, int E, int NB,
                                                  int* __restrict__ fillR, int* __restrict__ fillC,
                                                  unsigned int* __restrict__ RB,
                                                  unsigned char* __restrict__ CB) {
    __shared__ int cR[NBMAX], cC[NBMAX], bR[NBMAX], bC[NBMAX];
    int t = threadIdx.x;
    for (int i = t; i < NB; i += 1024) { cR[i] = 0; cC[i] = 0; }
    __syncthreads();
    int per = (E + gridDim.x - 1) / gridDim.x;
    int e0 = blockIdx.x * per, e1 = min(E, e0 + per);
    for (int e = e0 + t; e < e1; e += 1024) {
        atomicAdd(&cR[row[e] >> 8], 1);
        atomicAdd(&cC[col[e] >> 8], 1);
    }
    __syncthreads();
    int stag = (int)((blockIdx.x * 37u) % (unsigned)NB);
    for (int j = t; j < NB; j += 1024) {
        int i = j + stag; if (i >= NB) i -= NB;
        bR[i] = cR[i] ? atomicAdd(&fillR[i], cR[i]) : 0;
        bC[i] = cC[i] ? atomicAdd(&fillC[i], cC[i]) : 0;
    }
    __syncthreads();
    for (int i = t; i < NB; i += 1024) { cR[i] = 0; cC[i] = 0; }
    __syncthreads();
    for (int e = e0 + t; e < e1; e += 1024) {    // chunk is L2-hot on re-read
        int r = row[e], c = col[e];
        int br = r >> 8, bc = c >> 8;
        int pR = bR[br] + atomicAdd(&cR[br], 1);
        if (pR < BCAP) RB[(size_t)br * BCAP + pR] = ((unsigned)c << 8) | ((unsigned)r & 255u);
        int pC = bC[bc] + atomicAdd(&cC[bc], 1);
        if (pC < BCAP) CB[(size_t)bc * BCAP + pC] = (unsigned char)(c & 255);
    }
}

// ---------------- Pass B: per-bucket CSR build + col-degree -> dinv ----------------
__global__ __launch_bounds__(1024) void build_csr(const unsigned int* __restrict__ RB,
                                                  const unsigned char* __restrict__ CB,
                                                  const int* __restrict__ fillR,
                                                  const int* __restrict__ fillC,
                                                  int* __restrict__ rowptr, int* __restrict__ indeg,
                                                  float* __restrict__ dinv, int* __restrict__ csr,
                                                  int n, int NB) {
    __shared__ int cnt[256], start[256], bump[256];
    __shared__ int wsum[4];
    __shared__ int s_base;
    int b = blockIdx.x, t = threadIdx.x;
    int node0 = b << 8;

    // inline exclusive prefix of bucket totals (wave 0)
    if (t < 64) {
        int pre = 0;
        for (int j = t; j < b; j += 64) pre += min(fillR[j], BCAP);
        #pragma unroll
        for (int off = 32; off; off >>= 1) pre += __shfl_down(pre, off, 64);
        if (t == 0) s_base = pre;
    }
    if (t < 256) { cnt[t] = 0; bump[t] = 0; }
    __syncthreads();

    int m = min(fillR[b], BCAP);
    const unsigned int* src = RB + (size_t)b * BCAP;
    for (int i = t; i < m; i += 1024)
        atomicAdd(&cnt[src[i] & 255u], 1);
    __syncthreads();

    int my = (t < 256) ? cnt[t] : 0;
    int lane = t & 63, w = (t >> 6) & 3;
    int x = my;
    #pragma unroll
    for (int off = 1; off < 64; off <<= 1) {
        int y = __shfl_up(x, off, 64);
        if (lane >= off) x += y;
    }
    if (t < 256 && lane == 63) wsum[w] = x;
    __syncthreads();
    int base = s_base;
    if (t < 256) {
        int wb = 0;
        #pragma unroll
        for (int i = 0; i < 4; i++) if (i < w) wb += wsum[i];
        int excl = wb + x - my;
        start[t] = excl;
        int v = node0 + t;
        if (v < n) { rowptr[v] = base + excl; indeg[v] = my; }
    }
    __syncthreads();
    for (int i = t; i < m; i += 1024) {
        unsigned en = src[i];
        int local = (int)(en & 255u);
        int c = (int)(en >> 8);
        int pos = base + start[local] + atomicAdd(&bump[local], 1);
        csr[pos] = c;
    }
    __syncthreads();
    if (t < 256) cnt[t] = 0;
    __syncthreads();
    int mc = min(fillC[b], BCAP);
    const unsigned char* sc = CB + (size_t)b * BCAP;
    for (int i = t; i < mc; i += 1024)
        atomicAdd(&cnt[(int)sc[i]], 1);
    __syncthreads();
    int v = node0 + t;
    if (t < 256 && v < n) dinv[v] = rsqrtf((float)(cnt[t] + 1));
}

// ---------------- dense: Z(bf16, split halves) = (X @ W) * dinv[:,None] ----------------
// Block = 64 nodes x 64 outputs. lane = node; wave w owns outputs [16w,16w+16).
// W rows are wave-uniform -> scalar s_load.
template <int K>
__global__ __launch_bounds__(256) void gemm_scale(const float* __restrict__ X,
                                                  const float* __restrict__ W,
                                                  const float* __restrict__ dinv,
                                                  unsigned* __restrict__ Zlo,
                                                  unsigned* __restrict__ Zhi, int n) {
    constexpr int KP = K + 4;
    __shared__ __align__(16) float xs[64 * KP];
    int v0 = blockIdx.x * 64;
    int t = threadIdx.x;

    constexpr int C4 = K / 4;
    for (int idx = t; idx < 64 * C4; idx += 256) {
        int i = idx / C4, c = idx % C4;
        int v = v0 + i;
        float4 val = (v < n) ? ((const float4*)(X + (size_t)v * K))[c]
                             : make_float4(0.f, 0.f, 0.f, 0.f);
        *(float4*)&xs[i * KP + c * 4] = val;
    }
    __syncthreads();

    int lane = t & 63;
    int wave = __builtin_amdgcn_readfirstlane(t >> 6);
    int j0 = wave * 16;
    float acc[16];
    #pragma unroll
    for (int jj = 0; jj < 16; jj++) acc[jj] = 0.f;

    const float* xrow = &xs[lane * KP];
    #pragma unroll 2
    for (int k = 0; k < K; k += 4) {
        float4 xv = *(const float4*)&xrow[k];
        #pragma unroll
        for (int kk = 0; kk < 4; kk++) {
            float xk = (&xv.x)[kk];
            const float* wrow = W + (k + kk) * 64 + j0;   // wave-uniform -> s_load
            #pragma unroll
            for (int jj = 0; jj < 16; jj++)
                acc[jj] = fmaf(xk, wrow[jj], acc[jj]);
        }
    }

    float dv = (v0 + lane < n) ? dinv[v0 + lane] : 0.f;
    __syncthreads();
    unsigned* zs32 = (unsigned*)xs;                // 64 nodes x 32 uints, rotate-swizzled
    #pragma unroll
    for (int p = 0; p < 8; p++) {
        int pl = (j0 >> 1) + p;
        int phys = (pl + lane) & 31;
        zs32[lane * 32 + phys] = pack_bf16(acc[2 * p] * dv, acc[2 * p + 1] * dv);
    }
    __syncthreads();
    for (int idx = t; idx < 2048; idx += 256) {
        int i = idx >> 5, c = idx & 31;
        int v = v0 + i;
        if (v < n) {
            unsigned val = zs32[i * 32 + ((c + i) & 31)];
            if (c < 16) Zlo[(size_t)v * 16 + c] = val;
            else        Zhi[(size_t)v * 16 + (c - 16)] = val;
        }
    }
}

// ---------------- sparse aggregate over one feature-half (2 nodes per wave) ----------------
__global__ __launch_bounds__(256) void aggregate_half(const ushort* __restrict__ Zh,
                                                      const int* __restrict__ rowptr,
                                                      const int* __restrict__ indeg,
                                                      const int* __restrict__ csr,
                                                      const float* __restrict__ dinv,
                                                      const float* __restrict__ bias,
                                                      float* __restrict__ Xout,
                                                      int n, int h) {
    int t = threadIdx.x;
    int wave = t >> 6, lane = t & 63;
    int half = lane >> 5, fl = lane & 31;
    int v = blockIdx.x * 8 + wave * 2 + half;
    bool alive = (v < n);
    int vv = alive ? v : 0;
    int s = rowptr[vv];
    int c = alive ? indeg[vv] : 0;

    float acc = bf16_to_f32(Zh[(size_t)vv * 32 + fl]);   // self-loop
    int cO = __shfl_xor(c, 32, 64);
    int cn = min(c, cO);                                 // both halves active: no guards
    int i = 0;
    for (; i + 3 < cn; i += 4) {
        int s0 = csr[s + i], s1 = csr[s + i + 1], s2 = csr[s + i + 2], s3 = csr[s + i + 3];
        float a0 = bf16_to_f32(Zh[(size_t)s0 * 32 + fl]);
        float a1 = bf16_to_f32(Zh[(size_t)s1 * 32 + fl]);
        float a2 = bf16_to_f32(Zh[(size_t)s2 * 32 + fl]);
        float a3 = bf16_to_f32(Zh[(size_t)s3 * 32 + fl]);
        acc += (a0 + a1) + (a2 + a3);
    }
    for (; i < cn; i++) acc += bf16_to_f32(Zh[(size_t)csr[s + i] * 32 + fl]);
    for (; i < c; i++)  acc += bf16_to_f32(Zh[(size_t)csr[s + i] * 32 + fl]);  // divergent tail

    if (alive) {
        float val = fmaxf(acc * dinv[v] + bias[h * 32 + fl], 0.f);
        Xout[(size_t)v * 64 + h * 32 + fl] = val;
    }
}

// ---------------- fused pool (block per graph, batch sorted) + linear + softmax ----------------
__device__ __forceinline__ int lbound(const int* a, int n, int key) {
    int lo = 0, hi = n;
    while (lo < hi) { int mid = (lo + hi) >> 1; if (a[mid] < key) lo = mid + 1; else hi = mid; }
    return lo;
}

__global__ __launch_bounds__(256) void pool_head(const float* __restrict__ x1,
                                                 const float* __restrict__ x2,
                                                 const float* __restrict__ x3,
                                                 const int* __restrict__ batch,
                                                 const float* __restrict__ Wl,
                                                 const float* __restrict__ bl,
                                                 float* __restrict__ out, int n) {
    __shared__ int sb[2];
    __shared__ float red[4][64];
    __shared__ float ps[64];
    __shared__ float lg[10];
    int g = blockIdx.x, t = threadIdx.x;
    int wave = t >> 6, lane = t & 63;
    if (t < 2) sb[t] = lbound(batch, n, g + t);
    __syncthreads();
    int s0 = sb[0], s1 = sb[1];
    float acc = 0.f;
    for (int v = s0 + wave; v < s1; v += 4)
        acc += x1[(size_t)v * 64 + lane] + x2[(size_t)v * 64 + lane] + x3[(size_t)v * 64 + lane];
    red[wave][lane] = acc;
    __syncthreads();
    if (t < 64) {
        int c = s1 - s0;
        float denom = 3.0f * (float)(c > 1 ? c : 1);
        ps[t] = (red[0][t] + red[1][t] + red[2][t] + red[3][t]) / denom;
    }
    __syncthreads();
    if (t < 10) {
        float a = bl[t];
        #pragma unroll 8
        for (int f = 0; f < 64; f++) a += ps[f] * Wl[f * 10 + t];
        lg[t] = a;
    }
    __syncthreads();
    if (t < 10) {
        float mx = -1e30f;
        for (int j = 0; j < 10; j++) mx = fmaxf(mx, lg[j]);
        float e = expf(lg[t] - mx);
        float ss = 0.f;
        for (int j = 0; j < 10; j++) ss += expf(lg[j] - mx);
        out[g * 10 + t] = e / ss;
    }
}

extern "C" void kernel_launch(void* const* d_in, const int* in_sizes, int n_in,
                              void* d_out, int out_size, void* d_ws, size_t ws_size,
                              hipStream_t stream) {
    const float* feats = (const float*)d_in[0];
    const int*   eidx  = (const int*)d_in[1];
    const int*   batch = (const int*)d_in[2];
    const float* W1 = (const float*)d_in[4];
    const float* b1 = (const float*)d_in[5];
    const float* W2 = (const float*)d_in[6];
    const float* b2 = (const float*)d_in[7];
    const float* W3 = (const float*)d_in[8];
    const float* b3 = (const float*)d_in[9];
    const float* Wl = (const float*)d_in[10];
    const float* bl = (const float*)d_in[11];
    float* out = (float*)d_out;

    int n = in_sizes[0] / 128;
    int E = in_sizes[1] / 2;
    int G = out_size / 10;
    int NB = ((n - 1) >> 8) + 1;
    const int* row = eidx;       // destination
    const int* col = eidx + E;   // source

    char* ws = (char*)d_ws;
    size_t o = 0;
    size_t o_fill    = o; o += 2 * NBMAX * 4;           // fillR | fillC (zeroed)
    size_t o_rowptr  = o; o += ALIGN_UP((size_t)n * 4, 256);
    size_t o_indeg   = o; o += ALIGN_UP((size_t)n * 4, 256);
    size_t o_dinv    = o; o += ALIGN_UP((size_t)n * 4, 256);
    size_t o_csr     = o; o += ALIGN_UP((size_t)E * 4, 256);
    size_t o_zlo     = o; o += ALIGN_UP((size_t)n * 64, 256);   // bf16 half: n x 16 uints
    size_t o_zhi     = o; o += ALIGN_UP((size_t)n * 64, 256);
    size_t o_union   = o;
    size_t rb_bytes  = (size_t)NBMAX * BCAP * 4;
    size_t xl_bytes  = ALIGN_UP((size_t)n * 64 * 4, 256);
    (void)ws_size; (void)n_in;

    int*   fillR   = (int*)(ws + o_fill);
    int*   fillC   = fillR + NBMAX;
    int*   rowptr  = (int*)(ws + o_rowptr);
    int*   indeg   = (int*)(ws + o_indeg);
    float* dinv    = (float*)(ws + o_dinv);
    int*   csr     = (int*)(ws + o_csr);
    unsigned* zlo  = (unsigned*)(ws + o_zlo);
    unsigned* zhi  = (unsigned*)(ws + o_zhi);
    unsigned int*  RB = (unsigned int*)(ws + o_union);
    unsigned char* CB = (unsigned char*)(ws + o_union + rb_bytes);
    float* x1 = (float*)(ws + o_union);
    float* x2 = (float*)(ws + o_union + xl_bytes);
    float* x3 = (float*)(ws + o_union + 2 * xl_bytes);

    hipMemsetAsync(ws + o_fill, 0, 2 * NBMAX * 4, stream);

    int gridG = (n + 63) / 64;   // gemm: 64 nodes per block
    int gridA = (n + 7) / 8;     // aggregate: 8 nodes per block (2 per wave)

    bin_edges<<<256, 1024, 0, stream>>>(row, col, E, NB, fillR, fillC, RB, CB);
    build_csr<<<NB, 1024, 0, stream>>>(RB, CB, fillR, fillC,
                                       rowptr, indeg, dinv, csr, n, NB);

    // conv1
    gemm_scale<128><<<gridG, 256, 0, stream>>>(feats, W1, dinv, zlo, zhi, n);
    aggregate_half<<<gridA, 256, 0, stream>>>((const ushort*)zlo, rowptr, indeg, csr, dinv, b1, x1, n, 0);
    aggregate_half<<<gridA, 256, 0, stream>>>((const ushort*)zhi, rowptr, indeg, csr, dinv, b1, x1, n, 1);
    // conv2
    gemm_scale<64><<<gridG, 256, 0, stream>>>(x1, W2, dinv, zlo, zhi, n);
    aggregate_half<<<gridA, 256, 0, stream>>>((const ushort*)zlo, rowptr, indeg, csr, dinv, b2, x2, n, 0);
    aggregate_half<<<gridA, 256, 0, stream>>>((const ushort*)zhi, rowptr, indeg, csr, dinv, b2, x2, n, 1);
    // conv3
    gemm_scale<64><<<gridG, 256, 0, stream>>>(x2, W3, dinv, zlo, zhi, n);
    aggregate_half<<<gridA, 256, 0, stream>>>((const ushort*)zlo, rowptr, indeg, csr, dinv, b3, x3, n, 0);
    aggregate_half<<<gridA, 256, 0, stream>>>((const ushort*)zhi, rowptr, indeg, csr, dinv, b3, x3, n, 1);

    pool_head<<<G, 256, 0, stream>>>(x1, x2, x3, batch, Wl, bl, out, n);
}

// Round 6
// 463.269 us; speedup vs baseline: 1.6111x; 1.6111x over previous
//
#include <hip/hip_runtime.h>
#include <hip/hip_bf16.h>

// GCN: 3x GCNConv(relu) -> mean over layers -> global mean pool -> linear -> softmax
// N=100000, E=3200000, F_IN=128, F_HID=64, F_OUT=10, G=1000.
//
// out[dst] = dinv[dst] * ( sum_{e: row[e]=dst} z[col[e]] + z[dst] ) + b,
// z = (x @ W) * dinv[:,None], dinv = rsqrt(deg_col + 1).
//
// R5 crashed with SIGABRT (likely GPU memory fault) with no counter data; the
// design is the union of R3/R4 components that individually passed. R6 =
// same design + hardening: guarded csr writes (E bound) and clamped gather
// indices in aggregate, so any latent CSR hole reads in-bounds instead of
// faulting at poison 0xAAAAAAAA.

#define ALIGN_UP(x, a) (((x) + (a) - 1) / (a) * (a))
#define NBMAX 512        // max buckets (node id >> 8), supports n <= 131072
#define BCAP  10240      // entries per bucket region (mean 8192, +22 sigma)

__device__ __forceinline__ float bf16_to_f32(ushort u) {
    return __uint_as_float(((unsigned)u) << 16);
}
__device__ __forceinline__ unsigned pack_bf16(float a, float b) {
    union { __hip_bfloat16 h; ushort u; } ua, ub;
    ua.h = __float2bfloat16(a); ub.h = __float2bfloat16(b);
    return (unsigned)ua.u | ((unsigned)ub.u << 16);
}

// ---------------- Pass A: bin edges; RB=(col<<8)|(row&255) uint, CB=col&255 uchar ----------------
__global__ __launch_bounds__(1024) void bin_edges(const int* __restrict__ row,
                                                  const int* __restrict__ col, int E, int NB,
                                                  int* __restrict__ fillR, int* __restrict__ fillC,
                                                  unsigned int* __restrict__ RB,
                                                  unsigned char* __restrict__ CB) {
    __shared__ int cR[NBMAX], cC[NBMAX], bR[NBMAX], bC[NBMAX];
    int t = threadIdx.x;
    for (int i = t; i < NB; i += 1024) { cR[i] = 0; cC[i] = 0; }
    __syncthreads();
    int per = (E + gridDim.x - 1) / gridDim.x;
    int e0 = blockIdx.x * per, e1 = min(E, e0 + per);
    for (int e = e0 + t; e < e1; e += 1024) {
        atomicAdd(&cR[row[e] >> 8], 1);
        atomicAdd(&cC[col[e] >> 8], 1);
    }
    __syncthreads();
    int stag = (int)((blockIdx.x * 37u) % (unsigned)NB);
    for (int j = t; j < NB; j += 1024) {
        int i = j + stag; if (i >= NB) i -= NB;
        bR[i] = cR[i] ? atomicAdd(&fillR[i], cR[i]) : 0;
        bC[i] = cC[i] ? atomicAdd(&fillC[i], cC[i]) : 0;
    }
    __syncthreads();
    for (int i = t; i < NB; i += 1024) { cR[i] = 0; cC[i] = 0; }
    __syncthreads();
    for (int e = e0 + t; e < e1; e += 1024) {    // chunk is L2-hot on re-read
        int r = row[e], c = col[e];
        int br = r >> 8, bc = c >> 8;
        int pR = bR[br] + atomicAdd(&cR[br], 1);
        if (pR < BCAP) RB[(size_t)br * BCAP + pR] = ((unsigned)c << 8) | ((unsigned)r & 255u);
        int pC = bC[bc] + atomicAdd(&cC[bc], 1);
        if (pC < BCAP) CB[(size_t)bc * BCAP + pC] = (unsigned char)(c & 255);
    }
}

// ---------------- Pass B: per-bucket CSR build + col-degree -> dinv ----------------
__global__ __launch_bounds__(1024) void build_csr(const unsigned int* __restrict__ RB,
                                                  const unsigned char* __restrict__ CB,
                                                  const int* __restrict__ fillR,
                                                  const int* __restrict__ fillC,
                                                  int* __restrict__ rowptr, int* __restrict__ indeg,
                                                  float* __restrict__ dinv, int* __restrict__ csr,
                                                  int n, int NB, int E) {
    __shared__ int cnt[256], start[256], bump[256];
    __shared__ int wsum[4];
    __shared__ int s_base;
    int b = blockIdx.x, t = threadIdx.x;
    int node0 = b << 8;

    // inline exclusive prefix of bucket totals (wave 0)
    if (t < 64) {
        int pre = 0;
        for (int j = t; j < b; j += 64) pre += min(fillR[j], BCAP);
        #pragma unroll
        for (int off = 32; off; off >>= 1) pre += __shfl_down(pre, off, 64);
        if (t == 0) s_base = pre;
    }
    if (t < 256) { cnt[t] = 0; bump[t] = 0; }
    __syncthreads();

    int m = min(fillR[b], BCAP);
    const unsigned int* src = RB + (size_t)b * BCAP;
    for (int i = t; i < m; i += 1024)
        atomicAdd(&cnt[src[i] & 255u], 1);
    __syncthreads();

    int my = (t < 256) ? cnt[t] : 0;
    int lane = t & 63, w = (t >> 6) & 3;
    int x = my;
    #pragma unroll
    for (int off = 1; off < 64; off <<= 1) {
        int y = __shfl_up(x, off, 64);
        if (lane >= off) x += y;
    }
    if (t < 256 && lane == 63) wsum[w] = x;
    __syncthreads();
    int base = s_base;
    if (t < 256) {
        int wb = 0;
        #pragma unroll
        for (int i = 0; i < 4; i++) if (i < w) wb += wsum[i];
        int excl = wb + x - my;
        start[t] = excl;
        int v = node0 + t;
        if (v < n) { rowptr[v] = base + excl; indeg[v] = my; }
    }
    __syncthreads();
    for (int i = t; i < m; i += 1024) {
        unsigned en = src[i];
        int local = (int)(en & 255u);
        int c = (int)(en >> 8);
        int pos = base + start[local] + atomicAdd(&bump[local], 1);
        if (pos < E) csr[pos] = c;                 // hardening: never write OOB
    }
    __syncthreads();
    if (t < 256) cnt[t] = 0;
    __syncthreads();
    int mc = min(fillC[b], BCAP);
    const unsigned char* sc = CB + (size_t)b * BCAP;
    for (int i = t; i < mc; i += 1024)
        atomicAdd(&cnt[(int)sc[i]], 1);
    __syncthreads();
    int v = node0 + t;
    if (t < 256 && v < n) dinv[v] = rsqrtf((float)(cnt[t] + 1));
}

// ---------------- dense: Z(bf16) = (X @ W) * dinv[:,None] ----------------
// Block = 64 nodes x 64 outputs. lane = node; wave w owns outputs [16w,16w+16).
// W rows are wave-uniform -> scalar s_load.
template <int K>
__global__ __launch_bounds__(256) void gemm_scale(const float* __restrict__ X,
                                                  const float* __restrict__ W,
                                                  const float* __restrict__ dinv,
                                                  unsigned* __restrict__ Z, int n) {
    constexpr int KP = K + 4;
    __shared__ __align__(16) float xs[64 * KP];
    int v0 = blockIdx.x * 64;
    int t = threadIdx.x;

    constexpr int C4 = K / 4;
    for (int idx = t; idx < 64 * C4; idx += 256) {
        int i = idx / C4, c = idx % C4;
        int v = v0 + i;
        float4 val = (v < n) ? ((const float4*)(X + (size_t)v * K))[c]
                             : make_float4(0.f, 0.f, 0.f, 0.f);
        *(float4*)&xs[i * KP + c * 4] = val;
    }
    __syncthreads();

    int lane = t & 63;
    int wave = __builtin_amdgcn_readfirstlane(t >> 6);
    int j0 = wave * 16;
    float acc[16];
    #pragma unroll
    for (int jj = 0; jj < 16; jj++) acc[jj] = 0.f;

    const float* xrow = &xs[lane * KP];
    #pragma unroll 2
    for (int k = 0; k < K; k += 4) {
        float4 xv = *(const float4*)&xrow[k];
        #pragma unroll
        for (int kk = 0; kk < 4; kk++) {
            float xk = (&xv.x)[kk];
            const float* wrow = W + (k + kk) * 64 + j0;   // wave-uniform -> s_load
            #pragma unroll
            for (int jj = 0; jj < 16; jj++)
                acc[jj] = fmaf(xk, wrow[jj], acc[jj]);
        }
    }

    float dv = (v0 + lane < n) ? dinv[v0 + lane] : 0.f;
    __syncthreads();
    // transpose via LDS (reuse xs) with rotate swizzle; store coalesced bf16 rows
    unsigned* zs32 = (unsigned*)xs;                // 64 nodes x 32 uints (2 bf16 each)
    #pragma unroll
    for (int p = 0; p < 8; p++) {
        int pl = (j0 >> 1) + p;                    // logical uint column
        int phys = (pl + lane) & 31;
        zs32[lane * 32 + phys] = pack_bf16(acc[2 * p] * dv, acc[2 * p + 1] * dv);
    }
    __syncthreads();
    for (int idx = t; idx < 2048; idx += 256) {
        int i = idx >> 5, c = idx & 31;
        int v = v0 + i;
        if (v < n) Z[(size_t)v * 32 + c] = zs32[i * 32 + ((c + i) & 31)];
    }
}

// ---------------- sparse aggregate + bias + relu (bf16 gather, full width) ----------------
// One wave per dst node; 64 lanes x 2B = one 128B line per edge. Unroll 8 for MLP.
__global__ __launch_bounds__(256) void aggregate(const ushort* __restrict__ Z,
                                                 const int* __restrict__ rowptr,
                                                 const int* __restrict__ indeg,
                                                 const int* __restrict__ csr,
                                                 const float* __restrict__ dinv,
                                                 const float* __restrict__ bias,
                                                 float* __restrict__ Xout, int n) {
    int wave = threadIdx.x >> 6;
    int lane = threadIdx.x & 63;
    int v = blockIdx.x * 4 + wave;
    if (v >= n) return;
    int vs = __builtin_amdgcn_readfirstlane(v);
    int nm1 = n - 1;

    float acc = bf16_to_f32(Z[(size_t)vs * 64 + lane]);   // self-loop
    int s = rowptr[vs], c = indeg[vs];
    int i = 0;
    for (; i + 7 < c; i += 8) {
        int idx[8];
        #pragma unroll
        for (int u = 0; u < 8; u++) idx[u] = min(csr[s + i + u], nm1);  // hardening clamp
        float a[8];
        #pragma unroll
        for (int u = 0; u < 8; u++) a[u] = bf16_to_f32(Z[(size_t)idx[u] * 64 + lane]);
        acc += ((a[0] + a[1]) + (a[2] + a[3])) + ((a[4] + a[5]) + (a[6] + a[7]));
    }
    for (; i + 1 < c; i += 2) {
        int s0 = min(csr[s + i], nm1), s1 = min(csr[s + i + 1], nm1);
        acc += bf16_to_f32(Z[(size_t)s0 * 64 + lane]) + bf16_to_f32(Z[(size_t)s1 * 64 + lane]);
    }
    if (i < c) acc += bf16_to_f32(Z[(size_t)min(csr[s + i], nm1) * 64 + lane]);

    float val = fmaxf(acc * dinv[vs] + bias[lane], 0.f);
    Xout[(size_t)vs * 64 + lane] = val;
}

// ---------------- fused pool (block per graph, batch sorted) + linear + softmax ----------------
__device__ __forceinline__ int lbound(const int* a, int n, int key) {
    int lo = 0, hi = n;
    while (lo < hi) { int mid = (lo + hi) >> 1; if (a[mid] < key) lo = mid + 1; else hi = mid; }
    return lo;
}

__global__ __launch_bounds__(256) void pool_head(const float* __restrict__ x1,
                                                 const float* __restrict__ x2,
                                                 const float* __restrict__ x3,
                                                 const int* __restrict__ batch,
                                                 const float* __restrict__ Wl,
                                                 const float* __restrict__ bl,
                                                 float* __restrict__ out, int n) {
    __shared__ int sb[2];
    __shared__ float red[4][64];
    __shared__ float ps[64];
    __shared__ float lg[10];
    int g = blockIdx.x, t = threadIdx.x;
    int wave = t >> 6, lane = t & 63;
    if (t < 2) sb[t] = lbound(batch, n, g + t);
    __syncthreads();
    int s0 = sb[0], s1 = sb[1];
    float acc = 0.f;
    for (int v = s0 + wave; v < s1; v += 4)
        acc += x1[(size_t)v * 64 + lane] + x2[(size_t)v * 64 + lane] + x3[(size_t)v * 64 + lane];
    red[wave][lane] = acc;
    __syncthreads();
    if (t < 64) {
        int c = s1 - s0;
        float denom = 3.0f * (float)(c > 1 ? c : 1);
        ps[t] = (red[0][t] + red[1][t] + red[2][t] + red[3][t]) / denom;
    }
    __syncthreads();
    if (t < 10) {
        float a = bl[t];
        #pragma unroll 8
        for (int f = 0; f < 64; f++) a += ps[f] * Wl[f * 10 + t];
        lg[t] = a;
    }
    __syncthreads();
    if (t < 10) {
        float mx = -1e30f;
        for (int j = 0; j < 10; j++) mx = fmaxf(mx, lg[j]);
        float e = expf(lg[t] - mx);
        float ss = 0.f;
        for (int j = 0; j < 10; j++) ss += expf(lg[j] - mx);
        out[g * 10 + t] = e / ss;
    }
}

extern "C" void kernel_launch(void* const* d_in, const int* in_sizes, int n_in,
                              void* d_out, int out_size, void* d_ws, size_t ws_size,
                              hipStream_t stream) {
    const float* feats = (const float*)d_in[0];
    const int*   eidx  = (const int*)d_in[1];
    const int*   batch = (const int*)d_in[2];
    const float* W1 = (const float*)d_in[4];
    const float* b1 = (const float*)d_in[5];
    const float* W2 = (const float*)d_in[6];
    const float* b2 = (const float*)d_in[7];
    const float* W3 = (const float*)d_in[8];
    const float* b3 = (const float*)d_in[9];
    const float* Wl = (const float*)d_in[10];
    const float* bl = (const float*)d_in[11];
    float* out = (float*)d_out;

    int n = in_sizes[0] / 128;
    int E = in_sizes[1] / 2;
    int G = out_size / 10;
    int NB = ((n - 1) >> 8) + 1;
    const int* row = eidx;       // destination
    const int* col = eidx + E;   // source

    char* ws = (char*)d_ws;
    size_t o = 0;
    size_t o_fill    = o; o += 2 * NBMAX * 4;           // fillR | fillC (zeroed)
    size_t o_rowptr  = o; o += ALIGN_UP((size_t)n * 4, 256);
    size_t o_indeg   = o; o += ALIGN_UP((size_t)n * 4, 256);
    size_t o_dinv    = o; o += ALIGN_UP((size_t)n * 4, 256);
    size_t o_csr     = o; o += ALIGN_UP((size_t)E * 4, 256);
    size_t o_z       = o; o += ALIGN_UP((size_t)n * 64 * 2, 256);   // bf16 Z
    size_t o_union   = o;
    size_t rb_bytes  = (size_t)NBMAX * BCAP * 4;
    size_t xl_bytes  = ALIGN_UP((size_t)n * 64 * 4, 256);
    (void)ws_size; (void)n_in;

    int*   fillR   = (int*)(ws + o_fill);
    int*   fillC   = fillR + NBMAX;
    int*   rowptr  = (int*)(ws + o_rowptr);
    int*   indeg   = (int*)(ws + o_indeg);
    float* dinv    = (float*)(ws + o_dinv);
    int*   csr     = (int*)(ws + o_csr);
    unsigned* z    = (unsigned*)(ws + o_z);
    unsigned int*  RB = (unsigned int*)(ws + o_union);
    unsigned char* CB = (unsigned char*)(ws + o_union + rb_bytes);
    float* x1 = (float*)(ws + o_union);
    float* x2 = (float*)(ws + o_union + xl_bytes);
    float* x3 = (float*)(ws + o_union + 2 * xl_bytes);

    hipMemsetAsync(ws + o_fill, 0, 2 * NBMAX * 4, stream);

    int gridG = (n + 63) / 64;   // gemm: 64 nodes per block
    int gridW = (n + 3) / 4;     // aggregate: one wave per node

    bin_edges<<<256, 1024, 0, stream>>>(row, col, E, NB, fillR, fillC, RB, CB);
    build_csr<<<NB, 1024, 0, stream>>>(RB, CB, fillR, fillC,
                                       rowptr, indeg, dinv, csr, n, NB, E);

    // conv1
    gemm_scale<128><<<gridG, 256, 0, stream>>>(feats, W1, dinv, z, n);
    aggregate<<<gridW, 256, 0, stream>>>((const ushort*)z, rowptr, indeg, csr, dinv, b1, x1, n);
    // conv2
    gemm_scale<64><<<gridG, 256, 0, stream>>>(x1, W2, dinv, z, n);
    aggregate<<<gridW, 256, 0, stream>>>((const ushort*)z, rowptr, indeg, csr, dinv, b2, x2, n);
    // conv3
    gemm_scale<64><<<gridG, 256, 0, stream>>>(x2, W3, dinv, z, n);
    aggregate<<<gridW, 256, 0, stream>>>((const ushort*)z, rowptr, indeg, csr, dinv, b3, x3, n);

    pool_head<<<G, 256, 0, stream>>>(x1, x2, x3, batch, Wl, bl, out, n);
}